// Round 7
// baseline (98.635 us; speedup 1.0000x reference)
//
#include <hip/hip_runtime.h>

// Problem constants (match the reference).
constexpr int B = 32, C = 256, H = 56, W = 56, K = 4;
constexpr int HW = H * W;                 // 3136 floats per (b,c) plane
constexpr int BC = B * C;                 // 8192 planes
constexpr long long IMG = (long long)BC * HW;  // 25,690,112 elements
constexpr int NP = 4;                     // planes per block (pipelined)

// Native clang vector type — accepted by __builtin_nontemporal_store.
typedef float f4 __attribute__((ext_vector_type(4)));

// Register set for one plane: 3 full rounds x 4 inputs + predicated tail.
// All indices below are compile-time -> SROA promotes to registers.
struct PlaneRegs { f4 v[16]; };

__device__ __forceinline__ void issue_loads(
    PlaneRegs& R,
    const f4* __restrict__ p0, const f4* __restrict__ p1,
    const f4* __restrict__ p2, const f4* __restrict__ p3,
    int i0, int i1, int i2, int i3, bool tail)
{
    R.v[ 0] = p0[i0]; R.v[ 1] = p1[i0]; R.v[ 2] = p2[i0]; R.v[ 3] = p3[i0];
    R.v[ 4] = p0[i1]; R.v[ 5] = p1[i1]; R.v[ 6] = p2[i1]; R.v[ 7] = p3[i1];
    R.v[ 8] = p0[i2]; R.v[ 9] = p1[i2]; R.v[10] = p2[i2]; R.v[11] = p3[i2];
    if (tail) {
        R.v[12] = p0[i3]; R.v[13] = p1[i3]; R.v[14] = p2[i3]; R.v[15] = p3[i3];
    } else {
        R.v[12] = 0.0f; R.v[13] = 0.0f; R.v[14] = 0.0f; R.v[15] = 0.0f;
    }
}

__device__ __forceinline__ f4 fuse1(const f4& a, const f4& b,
                                    const f4& c, const f4& d,
                                    float w0, float w1, float w2, float w3,
                                    float& usum)
{
    f4 o;
    o.x = w0 * a.x + w1 * b.x + w2 * c.x + w3 * d.x;
    o.y = w0 * a.y + w1 * b.y + w2 * c.y + w3 * d.y;
    o.z = w0 * a.z + w1 * b.z + w2 * c.z + w3 * d.z;
    o.w = w0 * a.w + w1 * b.w + w2 * c.w + w3 * d.w;
    usum += (a.x + b.x + c.x + d.x)
          + (a.y + b.y + c.y + d.y)
          + (a.z + b.z + c.z + d.z)
          + (a.w + b.w + c.w + d.w);
    return o;
}

__device__ __forceinline__ float consume(
    const PlaneRegs& R, float w0, float w1, float w2, float w3,
    f4* __restrict__ po, int i0, int i1, int i2, int i3, bool tail)
{
    float us = 0.0f;
    __builtin_nontemporal_store(fuse1(R.v[0],R.v[1],R.v[ 2],R.v[ 3],w0,w1,w2,w3,us), &po[i0]);
    __builtin_nontemporal_store(fuse1(R.v[4],R.v[5],R.v[ 6],R.v[ 7],w0,w1,w2,w3,us), &po[i1]);
    __builtin_nontemporal_store(fuse1(R.v[8],R.v[9],R.v[10],R.v[11],w0,w1,w2,w3,us), &po[i2]);
    if (tail)
        __builtin_nontemporal_store(fuse1(R.v[12],R.v[13],R.v[14],R.v[15],w0,w1,w2,w3,us), &po[i3]);
    return us;
}

// One block per NP consecutive planes, register double-buffered:
// loads for plane q+1 are issued BEFORE plane q is consumed, so the
// memory pipe never drains inside the block. No per-plane barrier —
// one __syncthreads at the very end for the cross-wave usum reduce.
__global__ __launch_bounds__(256) void sk_fuse_kernel(
    const float* __restrict__ x0, const float* __restrict__ x1,
    const float* __restrict__ x2, const float* __restrict__ x3,
    const float* __restrict__ logits,        // [K, B, C] = [K, BC]
    float* __restrict__ out,                 // [B, C, H, W]
    float* __restrict__ s_out,               // [B, C]
    float* __restrict__ usum_out)            // [B, C]
{
    const int tid = threadIdx.x;
    const int bc0 = blockIdx.x * NP;

    const int i0 = tid, i1 = tid + 256, i2 = tid + 512;
    const bool tail = (tid < 16);
    const int i3 = 768 + (tid & 15);

    // ---- softmax weights for all NP planes (block-uniform) ----
    float w0[NP], w1[NP], w2[NP], w3[NP];
    #pragma unroll
    for (int q = 0; q < NP; ++q) {
        const int bc = bc0 + q;
        const float l0 = logits[0 * BC + bc];
        const float l1 = logits[1 * BC + bc];
        const float l2 = logits[2 * BC + bc];
        const float l3 = logits[3 * BC + bc];
        const float m  = fmaxf(fmaxf(l0, l1), fmaxf(l2, l3));
        const float e0 = expf(l0 - m);
        const float e1 = expf(l1 - m);
        const float e2 = expf(l2 - m);
        const float e3 = expf(l3 - m);
        const float inv = 1.0f / (e0 + e1 + e2 + e3);
        w0[q] = e0 * inv; w1[q] = e1 * inv; w2[q] = e2 * inv; w3[q] = e3 * inv;
    }

    PlaneRegs A, Bf;
    float us[NP];

    // prologue: plane 0 loads
    {
        const size_t base = (size_t)bc0 * HW;
        issue_loads(A, (const f4*)(x0 + base), (const f4*)(x1 + base),
                       (const f4*)(x2 + base), (const f4*)(x3 + base),
                    i0, i1, i2, i3, tail);
    }

    #pragma unroll
    for (int q = 0; q < NP; ++q) {
        PlaneRegs& cur = (q & 1) ? Bf : A;
        PlaneRegs& nxt = (q & 1) ? A  : Bf;
        if (q + 1 < NP) {
            const size_t base = (size_t)(bc0 + q + 1) * HW;
            issue_loads(nxt, (const f4*)(x0 + base), (const f4*)(x1 + base),
                             (const f4*)(x2 + base), (const f4*)(x3 + base),
                        i0, i1, i2, i3, tail);
        }
        f4* __restrict__ po = (f4*)(out + (size_t)(bc0 + q) * HW);
        us[q] = consume(cur, w0[q], w1[q], w2[q], w3[q], po, i0, i1, i2, i3, tail);
    }

    // ---- reductions: wave shuffle for all NP, then one LDS pass ----
    #pragma unroll
    for (int off = 32; off > 0; off >>= 1) {
        #pragma unroll
        for (int q = 0; q < NP; ++q)
            us[q] += __shfl_down(us[q], off, 64);
    }

    __shared__ float wsum[4][NP];
    const int lane = tid & 63;
    const int wid  = tid >> 6;
    if (lane == 0) {
        #pragma unroll
        for (int q = 0; q < NP; ++q) wsum[wid][q] = us[q];
    }
    __syncthreads();
    if (tid < NP) {
        const float t = wsum[0][tid] + wsum[1][tid] + wsum[2][tid] + wsum[3][tid];
        usum_out[bc0 + tid] = t;
        s_out[bc0 + tid]    = t * (1.0f / HW);
    }
}

extern "C" void kernel_launch(void* const* d_in, const int* in_sizes, int n_in,
                              void* d_out, int out_size, void* d_ws, size_t ws_size,
                              hipStream_t stream) {
    const float* x0     = (const float*)d_in[0];
    const float* x1     = (const float*)d_in[1];
    const float* x2     = (const float*)d_in[2];
    const float* x3     = (const float*)d_in[3];
    const float* logits = (const float*)d_in[4];

    float* out      = (float*)d_out;          // [B,C,H,W]
    float* s_out    = out + IMG;              // [B,C]
    float* usum_out = s_out + BC;             // [B,C]

    sk_fuse_kernel<<<BC / NP, 256, 0, stream>>>(x0, x1, x2, x3, logits,
                                                out, s_out, usum_out);
}